// Round 1
// baseline (776.796 us; speedup 1.0000x reference)
//
#include <hip/hip_runtime.h>

namespace {
constexpr int kB    = 8192;
constexpr int kTH   = 11;
constexpr int kTP   = 80;
constexpr int kH    = 64;
constexpr int kRows = 2;   // rows (batch elements) per wave
}

__device__ __forceinline__ float fast_tanh(float x) {
    // tanh(x) = 1 - 2/(e^{2x}+1); e=inf -> 1, e=0 -> -1 (saturates safely, no NaN)
    float e = __expf(2.0f * x);
    return 1.0f - 2.0f / (e + 1.0f);
}

__device__ __forceinline__ void load_row64(float (&dst)[kH], const float* __restrict__ src) {
#pragma unroll
    for (int j = 0; j < kH / 4; ++j) {
        const float4 w = reinterpret_cast<const float4*>(src)[j];
        dst[4 * j + 0] = w.x;
        dst[4 * j + 1] = w.y;
        dst[4 * j + 2] = w.z;
        dst[4 * j + 3] = w.w;
    }
}

// y[lane] = init + sum_j W[lane][j] * hbuf[j]; hbuf is an LDS row read as
// same-address float4 broadcasts (conflict-free). 4 accumulators for ILP.
__device__ __forceinline__ float matvec64(const float (&W)[kH], const float* hbuf, float init) {
    float a0 = init, a1 = 0.f, a2 = 0.f, a3 = 0.f;
#pragma unroll
    for (int j = 0; j < kH / 4; ++j) {
        const float4 hv = reinterpret_cast<const float4*>(hbuf)[j];
        a0 = fmaf(W[4 * j + 0], hv.x, a0);
        a1 = fmaf(W[4 * j + 1], hv.y, a1);
        a2 = fmaf(W[4 * j + 2], hv.z, a2);
        a3 = fmaf(W[4 * j + 3], hv.w, a3);
    }
    return (a0 + a1) + (a2 + a3);
}

__global__ __launch_bounds__(64, 2) void traj_rnn_kernel(
    const float* __restrict__ x,
    const float* __restrict__ eWih0, const float* __restrict__ eWhh0,
    const float* __restrict__ ebih0, const float* __restrict__ ebhh0,
    const float* __restrict__ eWih1, const float* __restrict__ eWhh1,
    const float* __restrict__ ebih1, const float* __restrict__ ebhh1,
    const float* __restrict__ dWih0, const float* __restrict__ dWhh0,
    const float* __restrict__ dbih0, const float* __restrict__ dbhh0,
    const float* __restrict__ dWih1, const float* __restrict__ dWhh1,
    const float* __restrict__ dbih1, const float* __restrict__ dbhh1,
    const float* __restrict__ fcW, const float* __restrict__ fcb,
    float* __restrict__ out)
{
    const int lane = threadIdx.x;          // 0..63, one hidden unit per lane
    const int r0   = blockIdx.x * kRows;   // first batch row of this wave

    __shared__ __align__(16) float L1[kRows][kH];  // layer-0 hidden state per row
    __shared__ __align__(16) float L2[kRows][kH];  // layer-1 hidden state per row

#pragma unroll
    for (int r = 0; r < kRows; ++r) {
        L1[r][lane] = 0.f;
        L2[r][lane] = 0.f;
    }
    __builtin_amdgcn_wave_barrier();

    // ---------------- encoder (11 steps, layers interleaved per step) ----------------
    {
        const float2 wi = reinterpret_cast<const float2*>(eWih0)[lane];
        const float  W0a = wi.x, W0b = wi.y;
        const float  b0 = ebih0[lane] + ebhh0[lane];
        const float  b1 = ebih1[lane] + ebhh1[lane];
        float Whh0r[kH], Wih1r[kH], Whh1r[kH];
        load_row64(Whh0r, eWhh0 + lane * kH);
        load_row64(Wih1r, eWih1 + lane * kH);
        load_row64(Whh1r, eWhh1 + lane * kH);

        for (int t = 0; t < kTH; ++t) {
            float a[kRows], h1n[kRows], h2n[kRows];
#pragma unroll
            for (int r = 0; r < kRows; ++r) {
                const float x0 = x[(r0 + r) * (kTH * 2) + 2 * t + 0];
                const float x1 = x[(r0 + r) * (kTH * 2) + 2 * t + 1];
                a[r] = fmaf(W0a, x0, fmaf(W0b, x1, b0));
            }
#pragma unroll
            for (int r = 0; r < kRows; ++r)
                a[r] = matvec64(Whh0r, &L1[r][0], a[r]);
#pragma unroll
            for (int r = 0; r < kRows; ++r)
                h1n[r] = fast_tanh(a[r]);
            __builtin_amdgcn_wave_barrier();
#pragma unroll
            for (int r = 0; r < kRows; ++r)
                L1[r][lane] = h1n[r];
            __builtin_amdgcn_wave_barrier();
#pragma unroll
            for (int r = 0; r < kRows; ++r)
                a[r] = matvec64(Wih1r, &L1[r][0], b1);
#pragma unroll
            for (int r = 0; r < kRows; ++r)
                a[r] = matvec64(Whh1r, &L2[r][0], a[r]);
#pragma unroll
            for (int r = 0; r < kRows; ++r)
                h2n[r] = fast_tanh(a[r]);
            __builtin_amdgcn_wave_barrier();
#pragma unroll
            for (int r = 0; r < kRows; ++r)
                L2[r][lane] = h2n[r];
            __builtin_amdgcn_wave_barrier();
        }
    }

    __builtin_amdgcn_sched_barrier(0);  // keep decoder weight loads out of encoder live range

    // ---------------- decoder (80 autoregressive steps) ----------------
    {
        const float2 wi = reinterpret_cast<const float2*>(dWih0)[lane];
        const float  W0a = wi.x, W0b = wi.y;
        const float  b0 = dbih0[lane] + dbhh0[lane];
        const float  b1 = dbih1[lane] + dbhh1[lane];
        const float  fc0 = fcW[lane];        // fc_W[0][lane]
        const float  fc1 = fcW[kH + lane];   // fc_W[1][lane]
        const float  fb0 = fcb[0];
        const float  fb1 = fcb[1];
        float Whh0r[kH], Wih1r[kH], Whh1r[kH];
        load_row64(Whh0r, dWhh0 + lane * kH);
        load_row64(Wih1r, dWih1 + lane * kH);
        load_row64(Whh1r, dWhh1 + lane * kH);

        float in0[kRows], in1[kRows];
#pragma unroll
        for (int r = 0; r < kRows; ++r) {
            in0[r] = x[(r0 + r) * (kTH * 2) + 2 * (kTH - 1) + 0];
            in1[r] = x[(r0 + r) * (kTH * 2) + 2 * (kTH - 1) + 1];
        }

        for (int t = 0; t < kTP; ++t) {
            float a[kRows], h1n[kRows], h2n[kRows];
#pragma unroll
            for (int r = 0; r < kRows; ++r)
                a[r] = fmaf(W0a, in0[r], fmaf(W0b, in1[r], b0));
#pragma unroll
            for (int r = 0; r < kRows; ++r)
                a[r] = matvec64(Whh0r, &L1[r][0], a[r]);
#pragma unroll
            for (int r = 0; r < kRows; ++r)
                h1n[r] = fast_tanh(a[r]);
            __builtin_amdgcn_wave_barrier();
#pragma unroll
            for (int r = 0; r < kRows; ++r)
                L1[r][lane] = h1n[r];
            __builtin_amdgcn_wave_barrier();
#pragma unroll
            for (int r = 0; r < kRows; ++r)
                a[r] = matvec64(Wih1r, &L1[r][0], b1);
#pragma unroll
            for (int r = 0; r < kRows; ++r)
                a[r] = matvec64(Whh1r, &L2[r][0], a[r]);
#pragma unroll
            for (int r = 0; r < kRows; ++r)
                h2n[r] = fast_tanh(a[r]);
            __builtin_amdgcn_wave_barrier();
#pragma unroll
            for (int r = 0; r < kRows; ++r)
                L2[r][lane] = h2n[r];
            __builtin_amdgcn_wave_barrier();

            // fc head: pred = h2 @ fc_W.T + fc_b, reduced across the 64 lanes
            float p0[kRows], p1[kRows];
#pragma unroll
            for (int r = 0; r < kRows; ++r) {
                p0[r] = fc0 * h2n[r];
                p1[r] = fc1 * h2n[r];
            }
#pragma unroll
            for (int off = 32; off > 0; off >>= 1) {
#pragma unroll
                for (int r = 0; r < kRows; ++r) {
                    p0[r] += __shfl_xor(p0[r], off, 64);
                    p1[r] += __shfl_xor(p1[r], off, 64);
                }
            }
#pragma unroll
            for (int r = 0; r < kRows; ++r) {
                p0[r] += fb0;
                p1[r] += fb1;
                in0[r] = p0[r];   // autoregressive feedback
                in1[r] = p1[r];
            }
            if (lane == 0) {
#pragma unroll
                for (int r = 0; r < kRows; ++r) {
                    reinterpret_cast<float2*>(out)[(r0 + r) * kTP + t] =
                        make_float2(p0[r], p1[r]);
                }
            }
        }
    }
}

extern "C" void kernel_launch(void* const* d_in, const int* in_sizes, int n_in,
                              void* d_out, int out_size, void* d_ws, size_t ws_size,
                              hipStream_t stream) {
    const float* x     = (const float*)d_in[0];
    const float* eWih0 = (const float*)d_in[1];
    const float* eWhh0 = (const float*)d_in[2];
    const float* ebih0 = (const float*)d_in[3];
    const float* ebhh0 = (const float*)d_in[4];
    const float* eWih1 = (const float*)d_in[5];
    const float* eWhh1 = (const float*)d_in[6];
    const float* ebih1 = (const float*)d_in[7];
    const float* ebhh1 = (const float*)d_in[8];
    const float* dWih0 = (const float*)d_in[9];
    const float* dWhh0 = (const float*)d_in[10];
    const float* dbih0 = (const float*)d_in[11];
    const float* dbhh0 = (const float*)d_in[12];
    const float* dWih1 = (const float*)d_in[13];
    const float* dWhh1 = (const float*)d_in[14];
    const float* dbih1 = (const float*)d_in[15];
    const float* dbhh1 = (const float*)d_in[16];
    const float* fcW   = (const float*)d_in[17];
    const float* fcb   = (const float*)d_in[18];
    float* out = (float*)d_out;

    dim3 grid(kB / kRows);  // 4096 blocks, 1 wave each, 2 rows per wave
    dim3 block(64);
    traj_rnn_kernel<<<grid, block, 0, stream>>>(
        x, eWih0, eWhh0, ebih0, ebhh0, eWih1, eWhh1, ebih1, ebhh1,
        dWih0, dWhh0, dbih0, dbhh0, dWih1, dWhh1, dbih1, dbhh1,
        fcW, fcb, out);
}

// Round 2
// 554.129 us; speedup vs baseline: 1.4018x; 1.4018x over previous
//
#include <hip/hip_runtime.h>

namespace {
constexpr int kB    = 8192;
constexpr int kTH   = 11;
constexpr int kTP   = 80;
constexpr int kH    = 64;
constexpr int kRows = 2;   // batch rows per wave
}

__device__ __forceinline__ float fast_tanh(float x) {
    // tanh(x) = 1 - 2/(e^{2x}+1); saturates cleanly at +-1, no NaN
    float e = __expf(2.0f * x);
    return 1.0f - 2.0f / (e + 1.0f);
}

// wave-uniform broadcast of lane j's value via v_readlane -> SGPR (VALU pipe, no LDS)
__device__ __forceinline__ float bcast(float v, int j) {
    return __int_as_float(__builtin_amdgcn_readlane(__float_as_int(v), j));
}

__device__ __forceinline__ void load_row64(float (&dst)[kH], const float* __restrict__ src) {
#pragma unroll
    for (int j = 0; j < kH / 4; ++j) {
        const float4 w = reinterpret_cast<const float4*>(src)[j];
        dst[4 * j + 0] = w.x;
        dst[4 * j + 1] = w.y;
        dst[4 * j + 2] = w.z;
        dst[4 * j + 3] = w.w;
    }
}

// 256-reg budget (2 waves/EU): 192 weight regs + state must stay resident.
__global__ __attribute__((amdgpu_waves_per_eu(2, 2))) __launch_bounds__(64)
void traj_rnn_kernel(
    const float* __restrict__ x,
    const float* __restrict__ eWih0, const float* __restrict__ eWhh0,
    const float* __restrict__ ebih0, const float* __restrict__ ebhh0,
    const float* __restrict__ eWih1, const float* __restrict__ eWhh1,
    const float* __restrict__ ebih1, const float* __restrict__ ebhh1,
    const float* __restrict__ dWih0, const float* __restrict__ dWhh0,
    const float* __restrict__ dbih0, const float* __restrict__ dbhh0,
    const float* __restrict__ dWih1, const float* __restrict__ dWhh1,
    const float* __restrict__ dbih1, const float* __restrict__ dbhh1,
    const float* __restrict__ fcW, const float* __restrict__ fcb,
    float* __restrict__ out)
{
    const int lane = threadIdx.x;          // hidden unit owned by this lane
    const int r0   = blockIdx.x * kRows;   // first batch row of this wave

    float h1[kRows], h2[kRows], P1[kRows];  // P1 = Whh0 . h1 (pre-accumulated)
#pragma unroll
    for (int r = 0; r < kRows; ++r) { h1[r] = 0.f; h2[r] = 0.f; P1[r] = 0.f; }

    // ---------------- encoder: 11 steps ----------------
    {
        const float2 wi = reinterpret_cast<const float2*>(eWih0)[lane];
        const float  W0a = wi.x, W0b = wi.y;
        const float  b0 = ebih0[lane] + ebhh0[lane];
        const float  b1 = ebih1[lane] + ebhh1[lane];
        float Whh0r[kH], Wih1r[kH], Whh1r[kH];
        load_row64(Whh0r, eWhh0 + lane * kH);
        load_row64(Wih1r, eWih1 + lane * kH);
        load_row64(Whh1r, eWhh1 + lane * kH);

        for (int t = 0; t < kTH; ++t) {
#pragma unroll
            for (int r = 0; r < kRows; ++r) {
                const float* xr = x + (r0 + r) * (kTH * 2) + 2 * t;  // wave-uniform -> s_load
                const float x0 = xr[0], x1 = xr[1];
                // layer-1 pre-activation: pre-accumulated Whh0.h1 + input + bias
                h1[r] = fast_tanh(P1[r] + fmaf(W0a, x0, fmaf(W0b, x1, b0)));
            }
            // broadcast h1' once; feed BOTH Wih1 (this step) and Whh0 (next step)
#pragma unroll
            for (int r = 0; r < kRows; ++r) {
                float a0 = b1, a1 = 0.f, p0 = 0.f, p1 = 0.f;
#pragma unroll
                for (int j = 0; j < kH; j += 2) {
                    const float s0 = bcast(h1[r], j);
                    const float s1 = bcast(h1[r], j + 1);
                    a0 = fmaf(Wih1r[j],     s0, a0);
                    p0 = fmaf(Whh0r[j],     s0, p0);
                    a1 = fmaf(Wih1r[j + 1], s1, a1);
                    p1 = fmaf(Whh0r[j + 1], s1, p1);
                }
                P1[r] = p0 + p1;
                // Whh1 . h2 (old h2)
                float c0 = a0, c1 = a1;
#pragma unroll
                for (int j = 0; j < kH; j += 2) {
                    const float s0 = bcast(h2[r], j);
                    const float s1 = bcast(h2[r], j + 1);
                    c0 = fmaf(Whh1r[j],     s0, c0);
                    c1 = fmaf(Whh1r[j + 1], s1, c1);
                }
                h2[r] = fast_tanh(c0 + c1);
            }
        }
    }

    __builtin_amdgcn_sched_barrier(0);  // keep decoder weight loads out of encoder live range

    // ---------------- decoder: 80 autoregressive steps ----------------
    {
        const float2 wi = reinterpret_cast<const float2*>(dWih0)[lane];
        const float  W0a = wi.x, W0b = wi.y;
        const float  b0 = dbih0[lane] + dbhh0[lane];
        const float  b1 = dbih1[lane] + dbhh1[lane];
        const float  fc0 = fcW[lane];
        const float  fc1 = fcW[kH + lane];
        const float  fb0 = fcb[0];
        const float  fb1 = fcb[1];
        float Whh0r[kH], Wih1r[kH], Whh1r[kH];
        load_row64(Whh0r, dWhh0 + lane * kH);
        load_row64(Wih1r, dWih1 + lane * kH);
        load_row64(Whh1r, dWhh1 + lane * kH);

        // recompute P1 with decoder Whh0 from current h1 (one extra broadcast loop)
#pragma unroll
        for (int r = 0; r < kRows; ++r) {
            float p0 = 0.f, p1 = 0.f;
#pragma unroll
            for (int j = 0; j < kH; j += 2) {
                p0 = fmaf(Whh0r[j],     bcast(h1[r], j),     p0);
                p1 = fmaf(Whh0r[j + 1], bcast(h1[r], j + 1), p1);
            }
            P1[r] = p0 + p1;
        }

        float in0[kRows], in1[kRows];
#pragma unroll
        for (int r = 0; r < kRows; ++r) {
            const float* xr = x + (r0 + r) * (kTH * 2) + 2 * (kTH - 1);
            in0[r] = xr[0];
            in1[r] = xr[1];
        }

        for (int t = 0; t < kTP; ++t) {
            float p0v[kRows], p1v[kRows];
#pragma unroll
            for (int r = 0; r < kRows; ++r) {
                h1[r] = fast_tanh(P1[r] + fmaf(W0a, in0[r], fmaf(W0b, in1[r], b0)));

                float a0 = b1, a1 = 0.f, p0 = 0.f, p1 = 0.f;
#pragma unroll
                for (int j = 0; j < kH; j += 2) {
                    const float s0 = bcast(h1[r], j);
                    const float s1 = bcast(h1[r], j + 1);
                    a0 = fmaf(Wih1r[j],     s0, a0);
                    p0 = fmaf(Whh0r[j],     s0, p0);
                    a1 = fmaf(Wih1r[j + 1], s1, a1);
                    p1 = fmaf(Whh0r[j + 1], s1, p1);
                }
                P1[r] = p0 + p1;

                float c0 = a0, c1 = a1;
#pragma unroll
                for (int j = 0; j < kH; j += 2) {
                    const float s0 = bcast(h2[r], j);
                    const float s1 = bcast(h2[r], j + 1);
                    c0 = fmaf(Whh1r[j],     s0, c0);
                    c1 = fmaf(Whh1r[j + 1], s1, c1);
                }
                h2[r] = fast_tanh(c0 + c1);

                // fc head: butterfly reduce across 64 lanes
                float q0 = fc0 * h2[r];
                float q1 = fc1 * h2[r];
#pragma unroll
                for (int off = 32; off > 0; off >>= 1) {
                    q0 += __shfl_xor(q0, off, 64);
                    q1 += __shfl_xor(q1, off, 64);
                }
                q0 += fb0;
                q1 += fb1;
                in0[r] = q0;  // autoregressive feedback (all lanes hold it)
                in1[r] = q1;
                p0v[r] = q0;
                p1v[r] = q1;
            }
            if (lane == 0) {
#pragma unroll
                for (int r = 0; r < kRows; ++r) {
                    reinterpret_cast<float2*>(out)[(r0 + r) * kTP + t] =
                        make_float2(p0v[r], p1v[r]);
                }
            }
        }
    }
}

extern "C" void kernel_launch(void* const* d_in, const int* in_sizes, int n_in,
                              void* d_out, int out_size, void* d_ws, size_t ws_size,
                              hipStream_t stream) {
    const float* x     = (const float*)d_in[0];
    const float* eWih0 = (const float*)d_in[1];
    const float* eWhh0 = (const float*)d_in[2];
    const float* ebih0 = (const float*)d_in[3];
    const float* ebhh0 = (const float*)d_in[4];
    const float* eWih1 = (const float*)d_in[5];
    const float* eWhh1 = (const float*)d_in[6];
    const float* ebih1 = (const float*)d_in[7];
    const float* ebhh1 = (const float*)d_in[8];
    const float* dWih0 = (const float*)d_in[9];
    const float* dWhh0 = (const float*)d_in[10];
    const float* dbih0 = (const float*)d_in[11];
    const float* dbhh0 = (const float*)d_in[12];
    const float* dWih1 = (const float*)d_in[13];
    const float* dWhh1 = (const float*)d_in[14];
    const float* dbih1 = (const float*)d_in[15];
    const float* dbhh1 = (const float*)d_in[16];
    const float* fcW   = (const float*)d_in[17];
    const float* fcb   = (const float*)d_in[18];
    float* out = (float*)d_out;

    dim3 grid(kB / kRows);  // 4096 waves, 1 per block, 2 rows each
    dim3 block(64);
    traj_rnn_kernel<<<grid, block, 0, stream>>>(
        x, eWih0, eWhh0, ebih0, ebhh0, eWih1, eWhh1, ebih1, ebhh1,
        dWih0, dWhh0, dbih0, dbhh0, dWih1, dWhh1, dbih1, dbhh1,
        fcW, fcb, out);
}

// Round 3
// 353.999 us; speedup vs baseline: 2.1943x; 1.5653x over previous
//
#include <hip/hip_runtime.h>

typedef __attribute__((ext_vector_type(8))) __bf16 bf16x8;
typedef __attribute__((ext_vector_type(4))) float  f32x4;

namespace {
constexpr int kB   = 8192;
constexpr int kTH  = 11;
constexpr int kTP  = 80;
constexpr int kM   = 16;          // batch rows per wave (MFMA M)
constexpr int kStr = 68;          // LDS row stride (floats): 2-way banks, 16B aligned
}

union FragU { bf16x8 v; unsigned int u[4]; };

__device__ __forceinline__ unsigned pack_hi16(unsigned a, unsigned b) {
    return (a >> 16) | (b & 0xFFFF0000u);   // low half = first elem's bf16
}

// fp32[8] -> hi bf16x8 (truncated) + lo bf16x8 (truncated remainder)
__device__ __forceinline__ void split8(const float* f, bf16x8& hi, bf16x8& lo) {
    FragU H, L;
#pragma unroll
    for (int w = 0; w < 4; ++w) {
        const unsigned u0 = __float_as_uint(f[2 * w + 0]);
        const unsigned u1 = __float_as_uint(f[2 * w + 1]);
        const float h0 = __uint_as_float(u0 & 0xFFFF0000u);
        const float h1 = __uint_as_float(u1 & 0xFFFF0000u);
        const unsigned l0 = __float_as_uint(f[2 * w + 0] - h0);  // exact
        const unsigned l1 = __float_as_uint(f[2 * w + 1] - h1);
        H.u[w] = pack_hi16(u0, u1);
        L.u[w] = pack_hi16(l0, l1);
    }
    hi = H.v;
    lo = L.v;
}

__device__ __forceinline__ bf16x8 zero_frag() {
    FragU z;
    z.u[0] = z.u[1] = z.u[2] = z.u[3] = 0u;
    return z.v;
}

// B-fragments for D = A(HxK) * B(KxN), B[k][n] = W[n][k], W row-major 64x64.
// B layout: n = lane&15 (+16*ntile), k = (lane>>4)*8 + j (+32*kchunk).
__device__ __forceinline__ void loadB(const float* __restrict__ W, int p, int q,
                                      bf16x8 (&Bh)[4][2], bf16x8 (&Bl)[4][2]) {
#pragma unroll
    for (int n = 0; n < 4; ++n) {
#pragma unroll
        for (int c = 0; c < 2; ++c) {
            const float* src = W + (n * 16 + p) * 64 + c * 32 + q * 8;
            const float4 a = reinterpret_cast<const float4*>(src)[0];
            const float4 b = reinterpret_cast<const float4*>(src)[1];
            float f[8] = {a.x, a.y, a.z, a.w, b.x, b.y, b.z, b.w};
            split8(f, Bh[n][c], Bl[n][c]);
        }
    }
}

// A-fragments of H (M=16 x K=64, fp32 in LDS, row stride kStr) for lane (p,q):
// m = p, k = c*32 + q*8 + j.
__device__ __forceinline__ void readA(const float* Hbuf, int p, int q,
                                      bf16x8 (&Ah)[2], bf16x8 (&Al)[2]) {
#pragma unroll
    for (int c = 0; c < 2; ++c) {
        const float* src = Hbuf + p * kStr + c * 32 + q * 8;
        const float4 a = reinterpret_cast<const float4*>(src)[0];
        const float4 b = reinterpret_cast<const float4*>(src)[1];
        float f[8] = {a.x, a.y, a.z, a.w, b.x, b.y, b.z, b.w};
        split8(f, Ah[c], Al[c]);
    }
}

// 3-term Markidis accumulate: D += Ah*Bh + Ah*Bl + Al*Bh
__device__ __forceinline__ f32x4 mfma3(bf16x8 ah, bf16x8 al, bf16x8 bh, bf16x8 bl, f32x4 acc) {
    acc = __builtin_amdgcn_mfma_f32_16x16x32_bf16(ah, bh, acc, 0, 0, 0);
    acc = __builtin_amdgcn_mfma_f32_16x16x32_bf16(ah, bl, acc, 0, 0, 0);
    acc = __builtin_amdgcn_mfma_f32_16x16x32_bf16(al, bh, acc, 0, 0, 0);
    return acc;
}

__device__ __forceinline__ float fast_tanh(float x) {
    const float e = __expf(2.0f * x);
    return 1.0f - 2.0f / (e + 1.0f);
}

__global__ __attribute__((amdgpu_waves_per_eu(1, 1))) __launch_bounds__(64)
void traj_rnn_kernel(
    const float* __restrict__ x,
    const float* __restrict__ eWih0, const float* __restrict__ eWhh0,
    const float* __restrict__ ebih0, const float* __restrict__ ebhh0,
    const float* __restrict__ eWih1, const float* __restrict__ eWhh1,
    const float* __restrict__ ebih1, const float* __restrict__ ebhh1,
    const float* __restrict__ dWih0, const float* __restrict__ dWhh0,
    const float* __restrict__ dbih0, const float* __restrict__ dbhh0,
    const float* __restrict__ dWih1, const float* __restrict__ dWhh1,
    const float* __restrict__ dbih1, const float* __restrict__ dbhh1,
    const float* __restrict__ fcW, const float* __restrict__ fcb,
    float* __restrict__ out)
{
    const int lane = threadIdx.x;
    const int p = lane & 15;        // C-col index / A-row (m) / B-n
    const int q = lane >> 4;        // C row-quad / A,B k-quad
    const int r0 = blockIdx.x * kM; // first batch row of this wave's tile

    __shared__ __align__(16) float Hbuf1[kM * kStr];
    __shared__ __align__(16) float Hbuf2[kM * kStr];
    __shared__ float xbuf[kM * kTH * 2];

    // stage this tile's x into LDS (coalesced)
    for (int i = lane; i < kM * kTH * 2; i += 64)
        xbuf[i] = x[r0 * (kTH * 2) + i];
    __builtin_amdgcn_wave_barrier();

    // persistent hidden state as MFMA A-fragments (hi/lo bf16)
    bf16x8 H1h[2], H1l[2], H2h[2], H2l[2];
#pragma unroll
    for (int c = 0; c < 2; ++c) {
        H1h[c] = zero_frag(); H1l[c] = zero_frag();
        H2h[c] = zero_frag(); H2l[c] = zero_frag();
    }

    // ================= encoder: 11 steps =================
    {
        float b0v[4], b1v[4], w0v[4], w1v[4];
#pragma unroll
        for (int n = 0; n < 4; ++n) {
            const int col = n * 16 + p;
            b0v[n] = ebih0[col] + ebhh0[col];
            b1v[n] = ebih1[col] + ebhh1[col];
            w0v[n] = eWih0[col * 2 + 0];
            w1v[n] = eWih0[col * 2 + 1];
        }
        bf16x8 B0h[4][2], B0l[4][2], B1h[4][2], B1l[4][2], B2h[4][2], B2l[4][2];
        loadB(eWhh0, p, q, B0h, B0l);
        loadB(eWih1, p, q, B1h, B1l);
        loadB(eWhh1, p, q, B2h, B2l);

#pragma unroll 1
        for (int t = 0; t < kTH; ++t) {
            float x0r[4], x1r[4];
#pragma unroll
            for (int r = 0; r < 4; ++r) {
                const float2 xv = *reinterpret_cast<const float2*>(
                    &xbuf[(4 * q + r) * (kTH * 2) + 2 * t]);
                x0r[r] = xv.x; x1r[r] = xv.y;
            }
            // layer 1: Whh0 . H1 (+ bias as C init)
            f32x4 acc1[4];
#pragma unroll
            for (int n = 0; n < 4; ++n) {
                f32x4 a = {b0v[n], b0v[n], b0v[n], b0v[n]};
#pragma unroll
                for (int c = 0; c < 2; ++c)
                    a = mfma3(H1h[c], H1l[c], B0h[n][c], B0l[n][c], a);
                acc1[n] = a;
            }
#pragma unroll
            for (int n = 0; n < 4; ++n)
#pragma unroll
                for (int r = 0; r < 4; ++r) {
                    const float v = fmaf(w0v[n], x0r[r], fmaf(w1v[n], x1r[r], acc1[n][r]));
                    Hbuf1[(4 * q + r) * kStr + n * 16 + p] = fast_tanh(v);
                }
            __builtin_amdgcn_wave_barrier();
            readA(Hbuf1, p, q, H1h, H1l);

            // layer 2: Wih1 . H1' + Whh1 . H2 (+ bias)
            f32x4 acc2[4];
#pragma unroll
            for (int n = 0; n < 4; ++n) {
                f32x4 a = {b1v[n], b1v[n], b1v[n], b1v[n]};
#pragma unroll
                for (int c = 0; c < 2; ++c)
                    a = mfma3(H1h[c], H1l[c], B1h[n][c], B1l[n][c], a);
#pragma unroll
                for (int c = 0; c < 2; ++c)
                    a = mfma3(H2h[c], H2l[c], B2h[n][c], B2l[n][c], a);
                acc2[n] = a;
            }
#pragma unroll
            for (int n = 0; n < 4; ++n)
#pragma unroll
                for (int r = 0; r < 4; ++r)
                    Hbuf2[(4 * q + r) * kStr + n * 16 + p] = fast_tanh(acc2[n][r]);
            __builtin_amdgcn_wave_barrier();
            readA(Hbuf2, p, q, H2h, H2l);
        }
    }

    __builtin_amdgcn_sched_barrier(0);

    // ================= decoder: 80 autoregressive steps =================
    {
        float b0v[4], b1v[4], w0v[4], w1v[4], fc0v[4], fc1v[4];
#pragma unroll
        for (int n = 0; n < 4; ++n) {
            const int col = n * 16 + p;
            b0v[n] = dbih0[col] + dbhh0[col];
            b1v[n] = dbih1[col] + dbhh1[col];
            w0v[n] = dWih0[col * 2 + 0];
            w1v[n] = dWih0[col * 2 + 1];
            fc0v[n] = fcW[col];
            fc1v[n] = fcW[64 + col];
        }
        const float fb0 = fcb[0];
        const float fb1 = fcb[1];
        bf16x8 B0h[4][2], B0l[4][2], B1h[4][2], B1l[4][2], B2h[4][2], B2l[4][2];
        loadB(dWhh0, p, q, B0h, B0l);
        loadB(dWih1, p, q, B1h, B1l);
        loadB(dWhh1, p, q, B2h, B2l);

        // decoder inputs start at x[:, -1, :]
        float in0r[4], in1r[4];
#pragma unroll
        for (int r = 0; r < 4; ++r) {
            const float2 xv = *reinterpret_cast<const float2*>(
                &xbuf[(4 * q + r) * (kTH * 2) + 2 * (kTH - 1)]);
            in0r[r] = xv.x; in1r[r] = xv.y;
        }

#pragma unroll 1
        for (int t = 0; t < kTP; ++t) {
            // layer 1
            f32x4 acc1[4];
#pragma unroll
            for (int n = 0; n < 4; ++n) {
                f32x4 a = {b0v[n], b0v[n], b0v[n], b0v[n]};
#pragma unroll
                for (int c = 0; c < 2; ++c)
                    a = mfma3(H1h[c], H1l[c], B0h[n][c], B0l[n][c], a);
                acc1[n] = a;
            }
#pragma unroll
            for (int n = 0; n < 4; ++n)
#pragma unroll
                for (int r = 0; r < 4; ++r) {
                    const float v = fmaf(w0v[n], in0r[r], fmaf(w1v[n], in1r[r], acc1[n][r]));
                    Hbuf1[(4 * q + r) * kStr + n * 16 + p] = fast_tanh(v);
                }
            __builtin_amdgcn_wave_barrier();
            readA(Hbuf1, p, q, H1h, H1l);

            // layer 2
            f32x4 acc2[4];
#pragma unroll
            for (int n = 0; n < 4; ++n) {
                f32x4 a = {b1v[n], b1v[n], b1v[n], b1v[n]};
#pragma unroll
                for (int c = 0; c < 2; ++c)
                    a = mfma3(H1h[c], H1l[c], B1h[n][c], B1l[n][c], a);
#pragma unroll
                for (int c = 0; c < 2; ++c)
                    a = mfma3(H2h[c], H2l[c], B2h[n][c], B2l[n][c], a);
                acc2[n] = a;
            }
            // tanh + fc partials + stash for A-read
            float q0p[4] = {0.f, 0.f, 0.f, 0.f};
            float q1p[4] = {0.f, 0.f, 0.f, 0.f};
#pragma unroll
            for (int n = 0; n < 4; ++n)
#pragma unroll
                for (int r = 0; r < 4; ++r) {
                    const float h = fast_tanh(acc2[n][r]);
                    Hbuf2[(4 * q + r) * kStr + n * 16 + p] = h;
                    q0p[r] = fmaf(fc0v[n], h, q0p[r]);
                    q1p[r] = fmaf(fc1v[n], h, q1p[r]);
                }
            __builtin_amdgcn_wave_barrier();

            // fc reduce across the 16 lanes of each row-quad group
#pragma unroll
            for (int r = 0; r < 4; ++r) {
#pragma unroll
                for (int off = 1; off < 16; off <<= 1) {
                    q0p[r] += __shfl_xor(q0p[r], off, 64);
                    q1p[r] += __shfl_xor(q1p[r], off, 64);
                }
                q0p[r] += fb0;
                q1p[r] += fb1;
                in0r[r] = q0p[r];   // autoregressive feedback
                in1r[r] = q1p[r];
            }
            if (p == 0) {
#pragma unroll
                for (int r = 0; r < 4; ++r)
                    reinterpret_cast<float2*>(out)[(r0 + 4 * q + r) * kTP + t] =
                        make_float2(q0p[r], q1p[r]);
            }
            readA(Hbuf2, p, q, H2h, H2l);
        }
    }
}

extern "C" void kernel_launch(void* const* d_in, const int* in_sizes, int n_in,
                              void* d_out, int out_size, void* d_ws, size_t ws_size,
                              hipStream_t stream) {
    const float* x     = (const float*)d_in[0];
    const float* eWih0 = (const float*)d_in[1];
    const float* eWhh0 = (const float*)d_in[2];
    const float* ebih0 = (const float*)d_in[3];
    const float* ebhh0 = (const float*)d_in[4];
    const float* eWih1 = (const float*)d_in[5];
    const float* eWhh1 = (const float*)d_in[6];
    const float* ebih1 = (const float*)d_in[7];
    const float* ebhh1 = (const float*)d_in[8];
    const float* dWih0 = (const float*)d_in[9];
    const float* dWhh0 = (const float*)d_in[10];
    const float* dbih0 = (const float*)d_in[11];
    const float* dbhh0 = (const float*)d_in[12];
    const float* dWih1 = (const float*)d_in[13];
    const float* dWhh1 = (const float*)d_in[14];
    const float* dbih1 = (const float*)d_in[15];
    const float* dbhh1 = (const float*)d_in[16];
    const float* fcW   = (const float*)d_in[17];
    const float* fcb   = (const float*)d_in[18];
    float* out = (float*)d_out;

    dim3 grid(kB / kM);   // 512 blocks x 1 wave, 16 rows each
    dim3 block(64);
    traj_rnn_kernel<<<grid, block, 0, stream>>>(
        x, eWih0, eWhh0, ebih0, ebhh0, eWih1, eWhh1, ebih1, ebhh1,
        dWih0, dWhh0, dbih0, dbhh0, dWih1, dWhh1, dbih1, dbhh1,
        fcW, fcb, out);
}

// Round 4
// 256.939 us; speedup vs baseline: 3.0233x; 1.3778x over previous
//
#include <hip/hip_runtime.h>

typedef __attribute__((ext_vector_type(8))) __bf16 bf16x8;
typedef __attribute__((ext_vector_type(4))) float  f32x4;

namespace {
constexpr int kB    = 8192;
constexpr int kTH   = 11;
constexpr int kTP   = 80;
constexpr int kM    = 16;    // batch rows per block (MFMA M)
constexpr int kStrH = 72;    // H-plane row stride in bf16 units (144 B: 16B-aligned, bank-balanced)
}

union FragU { bf16x8 v; unsigned u[4]; };

__device__ __forceinline__ bf16x8 zero_frag() {
    FragU z; z.u[0] = z.u[1] = z.u[2] = z.u[3] = 0u; return z.v;
}

__device__ __forceinline__ unsigned pack_hi16(unsigned a, unsigned b) {
    return (a >> 16) | (b & 0xFFFF0000u);
}

// fp32[8] -> hi bf16x8 (truncated) + lo bf16x8 (exact remainder, truncated)
__device__ __forceinline__ void split8(const float* f, bf16x8& hi, bf16x8& lo) {
    FragU H, L;
#pragma unroll
    for (int w = 0; w < 4; ++w) {
        const unsigned u0 = __float_as_uint(f[2 * w + 0]);
        const unsigned u1 = __float_as_uint(f[2 * w + 1]);
        const float h0 = __uint_as_float(u0 & 0xFFFF0000u);
        const float h1 = __uint_as_float(u1 & 0xFFFF0000u);
        const unsigned l0 = __float_as_uint(f[2 * w + 0] - h0);
        const unsigned l1 = __float_as_uint(f[2 * w + 1] - h1);
        H.u[w] = pack_hi16(u0, u1);
        L.u[w] = pack_hi16(l0, l1);
    }
    hi = H.v; lo = L.v;
}

// B-fragments (hi/lo) for this wave's single n-tile column `col`:
// B[k][col] = W[col][k]; lane (p,q) needs W[col][c*32 + q*8 + j], j=0..7.
__device__ __forceinline__ void loadB1(const float* __restrict__ W, int col, int q,
                                       bf16x8 (&Bh)[2], bf16x8 (&Bl)[2]) {
#pragma unroll
    for (int c = 0; c < 2; ++c) {
        const float* src = W + col * 64 + c * 32 + q * 8;
        const float4 a = reinterpret_cast<const float4*>(src)[0];
        const float4 b = reinterpret_cast<const float4*>(src)[1];
        float f[8] = {a.x, a.y, a.z, a.w, b.x, b.y, b.z, b.w};
        split8(f, Bh[c], Bl[c]);
    }
}

// split h into hi/lo bf16 and store to the two planes
__device__ __forceinline__ void write_h(unsigned short* hi, unsigned short* lo,
                                        int idx, float h) {
    const unsigned u = __float_as_uint(h);
    hi[idx] = (unsigned short)(u >> 16);
    const float hf = __uint_as_float(u & 0xFFFF0000u);
    const float l  = h - hf;                        // exact
    lo[idx] = (unsigned short)(__float_as_uint(l) >> 16);
}

__device__ __forceinline__ bf16x8 read_frag(const unsigned short* plane, int off) {
    return *reinterpret_cast<const bf16x8*>(plane + off);
}

// 3-term Markidis accumulate: D += Ah*Bh + Ah*Bl + Al*Bh
__device__ __forceinline__ f32x4 mfma3(bf16x8 ah, bf16x8 al, bf16x8 bh, bf16x8 bl, f32x4 acc) {
    acc = __builtin_amdgcn_mfma_f32_16x16x32_bf16(ah, bh, acc, 0, 0, 0);
    acc = __builtin_amdgcn_mfma_f32_16x16x32_bf16(ah, bl, acc, 0, 0, 0);
    acc = __builtin_amdgcn_mfma_f32_16x16x32_bf16(al, bh, acc, 0, 0, 0);
    return acc;
}

__device__ __forceinline__ float fast_tanh(float x) {
    const float e = __expf(2.0f * x);
    return 1.0f - 2.0f / (e + 1.0f);
}

__global__ __launch_bounds__(256) void traj_rnn_kernel(
    const float* __restrict__ x,
    const float* __restrict__ eWih0, const float* __restrict__ eWhh0,
    const float* __restrict__ ebih0, const float* __restrict__ ebhh0,
    const float* __restrict__ eWih1, const float* __restrict__ eWhh1,
    const float* __restrict__ ebih1, const float* __restrict__ ebhh1,
    const float* __restrict__ dWih0, const float* __restrict__ dWhh0,
    const float* __restrict__ dbih0, const float* __restrict__ dbhh0,
    const float* __restrict__ dWih1, const float* __restrict__ dWhh1,
    const float* __restrict__ dbih1, const float* __restrict__ dbhh1,
    const float* __restrict__ fcW, const float* __restrict__ fcb,
    float* __restrict__ out)
{
    const int tid  = threadIdx.x;
    const int wv   = tid >> 6;          // n-tile owned by this wave (0..3)
    const int lane = tid & 63;
    const int p    = lane & 15;         // A-m / C-col-within-tile
    const int q    = lane >> 4;         // k-quad / C row-quad
    const int col  = wv * 16 + p;       // this lane's hidden-unit column
    const int r0   = blockIdx.x * kM;

    __shared__ __align__(16) unsigned short Hhi1[kM * kStrH], Hlo1[kM * kStrH];
    __shared__ __align__(16) unsigned short Hhi2[kM * kStrH], Hlo2[kM * kStrH];
    __shared__ __align__(16) float xbuf[kM * kTH * 2];
    __shared__ float2 fcpart[4][kM];

    for (int i = tid; i < kM * kTH * 2; i += 256)
        xbuf[i] = x[r0 * (kTH * 2) + i];

    // persistent hidden-state A-fragments (hi/lo bf16)
    bf16x8 H1h[2], H1l[2], H2h[2], H2l[2];
#pragma unroll
    for (int c = 0; c < 2; ++c) {
        H1h[c] = zero_frag(); H1l[c] = zero_frag();
        H2h[c] = zero_frag(); H2l[c] = zero_frag();
    }
    __syncthreads();

    const int aoff = p * kStrH;  // A-fragment base for this lane's m-row

    // ================= encoder: 11 steps =================
    {
        const float b0 = ebih0[col] + ebhh0[col];
        const float b1 = ebih1[col] + ebhh1[col];
        const float w0 = eWih0[col * 2 + 0];
        const float w1 = eWih0[col * 2 + 1];
        bf16x8 B0h[2], B0l[2], B1h[2], B1l[2], B2h[2], B2l[2];
        loadB1(eWhh0, col, q, B0h, B0l);   // Whh0
        loadB1(eWih1, col, q, B1h, B1l);   // Wih1
        loadB1(eWhh1, col, q, B2h, B2l);   // Whh1

        f32x4 P1 = {b0, b0, b0, b0};       // b0 + Whh0 . h1 (h1 = 0 initially)

#pragma unroll 1
        for (int t = 0; t < kTH; ++t) {
            // layer 1: VALU only (P1 pre-accumulated last step)
#pragma unroll
            for (int r = 0; r < 4; ++r) {
                const float2 xv = *reinterpret_cast<const float2*>(
                    &xbuf[(4 * q + r) * (kTH * 2) + 2 * t]);
                const float h1 = fast_tanh(fmaf(w0, xv.x, fmaf(w1, xv.y, P1[r])));
                write_h(Hhi1, Hlo1, (4 * q + r) * kStrH + col, h1);
            }
            // layer-2 partial on OLD H2 (independent of h1') before the barrier
            f32x4 a2 = {b1, b1, b1, b1};
#pragma unroll
            for (int c = 0; c < 2; ++c)
                a2 = mfma3(H2h[c], H2l[c], B2h[c], B2l[c], a2);
            __syncthreads();   // h1' visible

#pragma unroll
            for (int c = 0; c < 2; ++c) {
                H1h[c] = read_frag(Hhi1, aoff + c * 32 + q * 8);
                H1l[c] = read_frag(Hlo1, aoff + c * 32 + q * 8);
            }
#pragma unroll
            for (int c = 0; c < 2; ++c)
                a2 = mfma3(H1h[c], H1l[c], B1h[c], B1l[c], a2);
            // pre-accumulate next step's layer-1 recurrent term (off critical path)
            f32x4 np = {b0, b0, b0, b0};
#pragma unroll
            for (int c = 0; c < 2; ++c)
                np = mfma3(H1h[c], H1l[c], B0h[c], B0l[c], np);
            P1 = np;

#pragma unroll
            for (int r = 0; r < 4; ++r) {
                const float h2 = fast_tanh(a2[r]);
                write_h(Hhi2, Hlo2, (4 * q + r) * kStrH + col, h2);
            }
            __syncthreads();   // h2' visible
#pragma unroll
            for (int c = 0; c < 2; ++c) {
                H2h[c] = read_frag(Hhi2, aoff + c * 32 + q * 8);
                H2l[c] = read_frag(Hlo2, aoff + c * 32 + q * 8);
            }
        }
    }

    // ================= decoder: 80 autoregressive steps =================
    {
        const float b0 = dbih0[col] + dbhh0[col];
        const float b1 = dbih1[col] + dbhh1[col];
        const float w0 = dWih0[col * 2 + 0];
        const float w1 = dWih0[col * 2 + 1];
        const float fc0 = fcW[col];
        const float fc1 = fcW[64 + col];
        const float fb0 = fcb[0];
        const float fb1 = fcb[1];
        bf16x8 B0h[2], B0l[2], B1h[2], B1l[2], B2h[2], B2l[2];
        loadB1(dWhh0, col, q, B0h, B0l);
        loadB1(dWih1, col, q, B1h, B1l);
        loadB1(dWhh1, col, q, B2h, B2l);

        // P1 for first decoder step: decoder Whh0 applied to encoder-final h1
        f32x4 P1 = {b0, b0, b0, b0};
#pragma unroll
        for (int c = 0; c < 2; ++c)
            P1 = mfma3(H1h[c], H1l[c], B0h[c], B0l[c], P1);

        float in0r[4], in1r[4];
#pragma unroll
        for (int r = 0; r < 4; ++r) {
            const float2 xv = *reinterpret_cast<const float2*>(
                &xbuf[(4 * q + r) * (kTH * 2) + 2 * (kTH - 1)]);
            in0r[r] = xv.x; in1r[r] = xv.y;
        }

#pragma unroll 1
        for (int t = 0; t < kTP; ++t) {
            // layer 1: VALU only
#pragma unroll
            for (int r = 0; r < 4; ++r) {
                const float h1 = fast_tanh(fmaf(w0, in0r[r], fmaf(w1, in1r[r], P1[r])));
                write_h(Hhi1, Hlo1, (4 * q + r) * kStrH + col, h1);
            }
            f32x4 a2 = {b1, b1, b1, b1};
#pragma unroll
            for (int c = 0; c < 2; ++c)
                a2 = mfma3(H2h[c], H2l[c], B2h[c], B2l[c], a2);
            __syncthreads();   // h1' visible

#pragma unroll
            for (int c = 0; c < 2; ++c) {
                H1h[c] = read_frag(Hhi1, aoff + c * 32 + q * 8);
                H1l[c] = read_frag(Hlo1, aoff + c * 32 + q * 8);
            }
#pragma unroll
            for (int c = 0; c < 2; ++c)
                a2 = mfma3(H1h[c], H1l[c], B1h[c], B1l[c], a2);
            f32x4 np = {b0, b0, b0, b0};
#pragma unroll
            for (int c = 0; c < 2; ++c)
                np = mfma3(H1h[c], H1l[c], B0h[c], B0l[c], np);
            P1 = np;

            float q0p[4], q1p[4];
#pragma unroll
            for (int r = 0; r < 4; ++r) {
                const float h2 = fast_tanh(a2[r]);
                write_h(Hhi2, Hlo2, (4 * q + r) * kStrH + col, h2);
                q0p[r] = fc0 * h2;
                q1p[r] = fc1 * h2;
            }
            // reduce fc partials over the 16 lanes of this wave's n-tile
#pragma unroll
            for (int off = 1; off < 16; off <<= 1) {
#pragma unroll
                for (int r = 0; r < 4; ++r) {
                    q0p[r] += __shfl_xor(q0p[r], off, 64);
                    q1p[r] += __shfl_xor(q1p[r], off, 64);
                }
            }
            if (p == 0) {
#pragma unroll
                for (int r = 0; r < 4; ++r)
                    fcpart[wv][4 * q + r] = make_float2(q0p[r], q1p[r]);
            }
            __syncthreads();   // h2' + fc partials visible

#pragma unroll
            for (int c = 0; c < 2; ++c) {
                H2h[c] = read_frag(Hhi2, aoff + c * 32 + q * 8);
                H2l[c] = read_frag(Hlo2, aoff + c * 32 + q * 8);
            }
            // final fc sum (broadcast reads), autoregressive feedback
#pragma unroll
            for (int r = 0; r < 4; ++r) {
                float s0 = fb0, s1 = fb1;
#pragma unroll
                for (int nn = 0; nn < 4; ++nn) {
                    const float2 f = fcpart[nn][4 * q + r];
                    s0 += f.x; s1 += f.y;
                }
                in0r[r] = s0; in1r[r] = s1;
            }
            if (wv == 0 && p == 0) {
#pragma unroll
                for (int r = 0; r < 4; ++r)
                    reinterpret_cast<float2*>(out)[(r0 + 4 * q + r) * kTP + t] =
                        make_float2(in0r[r], in1r[r]);
            }
        }
    }
}

extern "C" void kernel_launch(void* const* d_in, const int* in_sizes, int n_in,
                              void* d_out, int out_size, void* d_ws, size_t ws_size,
                              hipStream_t stream) {
    const float* x     = (const float*)d_in[0];
    const float* eWih0 = (const float*)d_in[1];
    const float* eWhh0 = (const float*)d_in[2];
    const float* ebih0 = (const float*)d_in[3];
    const float* ebhh0 = (const float*)d_in[4];
    const float* eWih1 = (const float*)d_in[5];
    const float* eWhh1 = (const float*)d_in[6];
    const float* ebih1 = (const float*)d_in[7];
    const float* ebhh1 = (const float*)d_in[8];
    const float* dWih0 = (const float*)d_in[9];
    const float* dWhh0 = (const float*)d_in[10];
    const float* dbih0 = (const float*)d_in[11];
    const float* dbhh0 = (const float*)d_in[12];
    const float* dWih1 = (const float*)d_in[13];
    const float* dWhh1 = (const float*)d_in[14];
    const float* dbih1 = (const float*)d_in[15];
    const float* dbhh1 = (const float*)d_in[16];
    const float* fcW   = (const float*)d_in[17];
    const float* fcb   = (const float*)d_in[18];
    float* out = (float*)d_out;

    dim3 grid(kB / kM);   // 512 blocks x 4 waves; wave n owns output cols 16n..16n+15
    dim3 block(256);
    traj_rnn_kernel<<<grid, block, 0, stream>>>(
        x, eWih0, eWhh0, ebih0, ebhh0, eWih1, eWhh1, ebih1, ebhh1,
        dWih0, dWhh0, dbih0, dbhh0, dWih1, dWhh1, dbih1, dbhh1,
        fcW, fcb, out);
}

// Round 5
// 201.684 us; speedup vs baseline: 3.8515x; 1.2740x over previous
//
#include <hip/hip_runtime.h>

typedef __attribute__((ext_vector_type(8))) __bf16 bf16x8;
typedef __attribute__((ext_vector_type(4))) float  f32x4;

namespace {
constexpr int kB    = 8192;
constexpr int kTH   = 11;
constexpr int kTP   = 80;
constexpr int kM    = 16;    // batch rows per block (MFMA M)
constexpr int kStrH = 72;    // H-plane row stride in bf16 units (144 B: 16B-aligned, 2-way banks)
}

union FragU { bf16x8 v; unsigned u[4]; };

__device__ __forceinline__ bf16x8 zero_frag() {
    FragU z; z.u[0] = z.u[1] = z.u[2] = z.u[3] = 0u; return z.v;
}

__device__ __forceinline__ unsigned pack_hi16(unsigned a, unsigned b) {
    return (a >> 16) | (b & 0xFFFF0000u);
}

// fp32[8] -> hi bf16x8 (truncated) + lo bf16x8 (exact remainder, truncated)
__device__ __forceinline__ void split8(const float* f, bf16x8& hi, bf16x8& lo) {
    FragU H, L;
#pragma unroll
    for (int w = 0; w < 4; ++w) {
        const unsigned u0 = __float_as_uint(f[2 * w + 0]);
        const unsigned u1 = __float_as_uint(f[2 * w + 1]);
        const float h0 = __uint_as_float(u0 & 0xFFFF0000u);
        const float h1 = __uint_as_float(u1 & 0xFFFF0000u);
        const unsigned l0 = __float_as_uint(f[2 * w + 0] - h0);
        const unsigned l1 = __float_as_uint(f[2 * w + 1] - h1);
        H.u[w] = pack_hi16(u0, u1);
        L.u[w] = pack_hi16(l0, l1);
    }
    hi = H.v; lo = L.v;
}

// B-fragments (hi/lo) for column `col`: B[k][col] = W[col][k].
__device__ __forceinline__ void loadB1(const float* __restrict__ W, int col, int q,
                                       bf16x8 (&Bh)[2], bf16x8 (&Bl)[2]) {
#pragma unroll
    for (int c = 0; c < 2; ++c) {
        const float* src = W + col * 64 + c * 32 + q * 8;
        const float4 a = reinterpret_cast<const float4*>(src)[0];
        const float4 b = reinterpret_cast<const float4*>(src)[1];
        float f[8] = {a.x, a.y, a.z, a.w, b.x, b.y, b.z, b.w};
        split8(f, Bh[c], Bl[c]);
    }
}

// fc B-fragment: only cols p<2 are real (fcW is 2x64); others zero.
__device__ __forceinline__ void loadBfc(const float* __restrict__ fcW, int p, int q,
                                        bf16x8 (&Bh)[2], bf16x8 (&Bl)[2]) {
#pragma unroll
    for (int c = 0; c < 2; ++c) {
        float f[8];
#pragma unroll
        for (int j = 0; j < 8; ++j)
            f[j] = (p < 2) ? fcW[p * 64 + c * 32 + q * 8 + j] : 0.f;
        split8(f, Bh[c], Bl[c]);
    }
}

// split h into hi/lo bf16 and store to the two planes
__device__ __forceinline__ void write_h(unsigned short* hi, unsigned short* lo,
                                        int idx, float h) {
    const unsigned u = __float_as_uint(h);
    hi[idx] = (unsigned short)(u >> 16);
    const float hf = __uint_as_float(u & 0xFFFF0000u);
    const float l  = h - hf;                        // exact
    lo[idx] = (unsigned short)(__float_as_uint(l) >> 16);
}

__device__ __forceinline__ bf16x8 read_frag(const unsigned short* plane, int off) {
    return *reinterpret_cast<const bf16x8*>(plane + off);
}

// 3-term Markidis accumulate: D += Ah*Bh + Ah*Bl + Al*Bh
__device__ __forceinline__ f32x4 mfma3(bf16x8 ah, bf16x8 al, bf16x8 bh, bf16x8 bl, f32x4 acc) {
    acc = __builtin_amdgcn_mfma_f32_16x16x32_bf16(ah, bh, acc, 0, 0, 0);
    acc = __builtin_amdgcn_mfma_f32_16x16x32_bf16(ah, bl, acc, 0, 0, 0);
    acc = __builtin_amdgcn_mfma_f32_16x16x32_bf16(al, bh, acc, 0, 0, 0);
    return acc;
}

__device__ __forceinline__ float fast_tanh(float x) {
    const float e = __expf(2.0f * x);
    return 1.0f - 2.0f / (e + 1.0f);
}

__global__ __launch_bounds__(256) void traj_rnn_kernel(
    const float* __restrict__ x,
    const float* __restrict__ eWih0, const float* __restrict__ eWhh0,
    const float* __restrict__ ebih0, const float* __restrict__ ebhh0,
    const float* __restrict__ eWih1, const float* __restrict__ eWhh1,
    const float* __restrict__ ebih1, const float* __restrict__ ebhh1,
    const float* __restrict__ dWih0, const float* __restrict__ dWhh0,
    const float* __restrict__ dbih0, const float* __restrict__ dbhh0,
    const float* __restrict__ dWih1, const float* __restrict__ dWhh1,
    const float* __restrict__ dbih1, const float* __restrict__ dbhh1,
    const float* __restrict__ fcW, const float* __restrict__ fcb,
    float* __restrict__ out)
{
    const int tid  = threadIdx.x;
    const int wv   = tid >> 6;          // n-tile owned by this wave (0..3)
    const int lane = tid & 63;
    const int p    = lane & 15;         // A-m / C-col-within-tile
    const int q    = lane >> 4;         // k-quad / C row-quad
    const int col  = wv * 16 + p;       // this lane's hidden-unit column
    const int r0   = blockIdx.x * kM;

    __shared__ __align__(16) unsigned short Hhi1[kM * kStrH], Hlo1[kM * kStrH];
    __shared__ __align__(16) unsigned short Hhi2[kM * kStrH], Hlo2[kM * kStrH];
    __shared__ __align__(16) float xbuf[kM * kTH * 2];

    for (int i = tid; i < kM * kTH * 2; i += 256)
        xbuf[i] = x[r0 * (kTH * 2) + i];

    bf16x8 H1h[2], H1l[2], H2h[2], H2l[2];
#pragma unroll
    for (int c = 0; c < 2; ++c) {
        H1h[c] = zero_frag(); H1l[c] = zero_frag();
        H2h[c] = zero_frag(); H2l[c] = zero_frag();
    }
    __syncthreads();

    const int aoff = p * kStrH;  // A-fragment base for this lane's m-row

    // ================= encoder: 11 steps =================
    {
        const float b0 = ebih0[col] + ebhh0[col];
        const float b1 = ebih1[col] + ebhh1[col];
        const float w0 = eWih0[col * 2 + 0];
        const float w1 = eWih0[col * 2 + 1];
        bf16x8 B0h[2], B0l[2], B1h[2], B1l[2], B2h[2], B2l[2];
        loadB1(eWhh0, col, q, B0h, B0l);   // Whh0
        loadB1(eWih1, col, q, B1h, B1l);   // Wih1
        loadB1(eWhh1, col, q, B2h, B2l);   // Whh1

        f32x4 P1 = {b0, b0, b0, b0};       // b0 + Whh0 . h1 (h1 = 0 initially)

#pragma unroll 1
        for (int t = 0; t < kTH; ++t) {
#pragma unroll
            for (int r = 0; r < 4; ++r) {
                const float2 xv = *reinterpret_cast<const float2*>(
                    &xbuf[(4 * q + r) * (kTH * 2) + 2 * t]);
                const float h1 = fast_tanh(fmaf(w0, xv.x, fmaf(w1, xv.y, P1[r])));
                write_h(Hhi1, Hlo1, (4 * q + r) * kStrH + col, h1);
            }
            // layer-2 partial on OLD H2 (independent of h1') before the barrier
            f32x4 a2 = {b1, b1, b1, b1};
#pragma unroll
            for (int c = 0; c < 2; ++c)
                a2 = mfma3(H2h[c], H2l[c], B2h[c], B2l[c], a2);
            __syncthreads();   // h1' visible

#pragma unroll
            for (int c = 0; c < 2; ++c) {
                H1h[c] = read_frag(Hhi1, aoff + c * 32 + q * 8);
                H1l[c] = read_frag(Hlo1, aoff + c * 32 + q * 8);
            }
#pragma unroll
            for (int c = 0; c < 2; ++c)
                a2 = mfma3(H1h[c], H1l[c], B1h[c], B1l[c], a2);
            f32x4 np = {b0, b0, b0, b0};
#pragma unroll
            for (int c = 0; c < 2; ++c)
                np = mfma3(H1h[c], H1l[c], B0h[c], B0l[c], np);
            P1 = np;

#pragma unroll
            for (int r = 0; r < 4; ++r) {
                const float h2 = fast_tanh(a2[r]);
                write_h(Hhi2, Hlo2, (4 * q + r) * kStrH + col, h2);
            }
            __syncthreads();   // h2' visible
#pragma unroll
            for (int c = 0; c < 2; ++c) {
                H2h[c] = read_frag(Hhi2, aoff + c * 32 + q * 8);
                H2l[c] = read_frag(Hlo2, aoff + c * 32 + q * 8);
            }
        }
    }

    // ================= decoder: 80 autoregressive steps =================
    {
        const float b0 = dbih0[col] + dbhh0[col];
        const float b1 = dbih1[col] + dbhh1[col];
        const float w0 = dWih0[col * 2 + 0];
        const float w1 = dWih0[col * 2 + 1];
        const float fb0 = fcb[0];
        const float fb1 = fcb[1];
        const float fbp = (p == 0) ? fb0 : fb1;   // for direct store from p<2 lanes
        bf16x8 B0h[2], B0l[2], B1h[2], B1l[2], B2h[2], B2l[2];
        bf16x8 BFh[2], BFl[2];
        loadB1(dWhh0, col, q, B0h, B0l);
        loadB1(dWih1, col, q, B1h, B1l);
        loadB1(dWhh1, col, q, B2h, B2l);
        loadBfc(fcW, p, q, BFh, BFl);

        // P1 for first decoder step: decoder Whh0 applied to encoder-final h1
        f32x4 P1 = {b0, b0, b0, b0};
#pragma unroll
        for (int c = 0; c < 2; ++c)
            P1 = mfma3(H1h[c], H1l[c], B0h[c], B0l[c], P1);

        float in0r[4], in1r[4];
#pragma unroll
        for (int r = 0; r < 4; ++r) {
            const float2 xv = *reinterpret_cast<const float2*>(
                &xbuf[(4 * q + r) * (kTH * 2) + 2 * (kTH - 1)]);
            in0r[r] = xv.x; in1r[r] = xv.y;
        }

        const int src0 = lane & 48;       // lane holding pred col 0 for this row-quad
        const int src1 = src0 | 1;        // pred col 1

#pragma unroll 1
        for (int t = 0; t < kTP; ++t) {
            // layer 1 (VALU only; P1 pre-accumulated)
#pragma unroll
            for (int r = 0; r < 4; ++r) {
                const float h1 = fast_tanh(fmaf(w0, in0r[r], fmaf(w1, in1r[r], P1[r])));
                write_h(Hhi1, Hlo1, (4 * q + r) * kStrH + col, h1);
            }
            // layer-2 partial on OLD H2 before the barrier
            f32x4 a2 = {b1, b1, b1, b1};
#pragma unroll
            for (int c = 0; c < 2; ++c)
                a2 = mfma3(H2h[c], H2l[c], B2h[c], B2l[c], a2);
            __syncthreads();   // h1' visible

#pragma unroll
            for (int c = 0; c < 2; ++c) {
                H1h[c] = read_frag(Hhi1, aoff + c * 32 + q * 8);
                H1l[c] = read_frag(Hlo1, aoff + c * 32 + q * 8);
            }
#pragma unroll
            for (int c = 0; c < 2; ++c)
                a2 = mfma3(H1h[c], H1l[c], B1h[c], B1l[c], a2);
            f32x4 np = {b0, b0, b0, b0};
#pragma unroll
            for (int c = 0; c < 2; ++c)
                np = mfma3(H1h[c], H1l[c], B0h[c], B0l[c], np);
            P1 = np;

#pragma unroll
            for (int r = 0; r < 4; ++r) {
                const float h2 = fast_tanh(a2[r]);
                write_h(Hhi2, Hlo2, (4 * q + r) * kStrH + col, h2);
            }
            __syncthreads();   // h2' visible

#pragma unroll
            for (int c = 0; c < 2; ++c) {
                H2h[c] = read_frag(Hhi2, aoff + c * 32 + q * 8);
                H2l[c] = read_frag(Hlo2, aoff + c * 32 + q * 8);
            }
            // fc head via MFMA: pred[4q+r][p] for p<2 (B cols >=2 are zero)
            f32x4 fcC = {0.f, 0.f, 0.f, 0.f};
#pragma unroll
            for (int c = 0; c < 2; ++c)
                fcC = mfma3(H2h[c], H2l[c], BFh[c], BFl[c], fcC);
            // broadcast pred to all lanes of the row-quad; autoregressive feedback
#pragma unroll
            for (int r = 0; r < 4; ++r) {
                in0r[r] = __shfl(fcC[r], src0, 64) + fb0;
                in1r[r] = __shfl(fcC[r], src1, 64) + fb1;
            }
            if (wv == 0 && p < 2) {
#pragma unroll
                for (int r = 0; r < 4; ++r)
                    out[((r0 + 4 * q + r) * kTP + t) * 2 + p] = fcC[r] + fbp;
            }
        }
    }
}

extern "C" void kernel_launch(void* const* d_in, const int* in_sizes, int n_in,
                              void* d_out, int out_size, void* d_ws, size_t ws_size,
                              hipStream_t stream) {
    const float* x     = (const float*)d_in[0];
    const float* eWih0 = (const float*)d_in[1];
    const float* eWhh0 = (const float*)d_in[2];
    const float* ebih0 = (const float*)d_in[3];
    const float* ebhh0 = (const float*)d_in[4];
    const float* eWih1 = (const float*)d_in[5];
    const float* eWhh1 = (const float*)d_in[6];
    const float* ebih1 = (const float*)d_in[7];
    const float* ebhh1 = (const float*)d_in[8];
    const float* dWih0 = (const float*)d_in[9];
    const float* dWhh0 = (const float*)d_in[10];
    const float* dbih0 = (const float*)d_in[11];
    const float* dbhh0 = (const float*)d_in[12];
    const float* dWih1 = (const float*)d_in[13];
    const float* dWhh1 = (const float*)d_in[14];
    const float* dbih1 = (const float*)d_in[15];
    const float* dbhh1 = (const float*)d_in[16];
    const float* fcW   = (const float*)d_in[17];
    const float* fcb   = (const float*)d_in[18];
    float* out = (float*)d_out;

    dim3 grid(kB / kM);   // 512 blocks x 4 waves; wave n owns output cols 16n..16n+15
    dim3 block(256);
    traj_rnn_kernel<<<grid, block, 0, stream>>>(
        x, eWih0, eWhh0, ebih0, ebhh0, eWih1, eWhh1, ebih1, ebhh1,
        dWih0, dWhh0, dbih0, dbhh0, dWih1, dWhh1, dbih1, dbhh1,
        fcW, fcb, out);
}

// Round 6
// 194.761 us; speedup vs baseline: 3.9885x; 1.0355x over previous
//
#include <hip/hip_runtime.h>

typedef __attribute__((ext_vector_type(8))) __bf16 bf16x8;
typedef __attribute__((ext_vector_type(4))) float  f32x4;

namespace {
constexpr int kB    = 8192;
constexpr int kTH   = 11;
constexpr int kTP   = 80;
constexpr int kM    = 16;    // batch rows per block (MFMA M)
constexpr int kStrH = 72;    // H-plane row stride in bf16 units (144 B: 16B-aligned, 2-way banks)
}

union FragU { bf16x8 v; unsigned u[4]; };

__device__ __forceinline__ bf16x8 zero_frag() {
    FragU z; z.u[0] = z.u[1] = z.u[2] = z.u[3] = 0u; return z.v;
}

__device__ __forceinline__ unsigned pack_hi16(unsigned a, unsigned b) {
    return (a >> 16) | (b & 0xFFFF0000u);
}

// fp32[8] -> hi bf16x8 (truncated) + lo bf16x8 (exact remainder, truncated)
__device__ __forceinline__ void split8(const float* f, bf16x8& hi, bf16x8& lo) {
    FragU H, L;
#pragma unroll
    for (int w = 0; w < 4; ++w) {
        const unsigned u0 = __float_as_uint(f[2 * w + 0]);
        const unsigned u1 = __float_as_uint(f[2 * w + 1]);
        const float h0 = __uint_as_float(u0 & 0xFFFF0000u);
        const float h1 = __uint_as_float(u1 & 0xFFFF0000u);
        const unsigned l0 = __float_as_uint(f[2 * w + 0] - h0);
        const unsigned l1 = __float_as_uint(f[2 * w + 1] - h1);
        H.u[w] = pack_hi16(u0, u1);
        L.u[w] = pack_hi16(l0, l1);
    }
    hi = H.v; lo = L.v;
}

// B-fragments (hi/lo) for column `col`: B[k][col] = W[col][k].
__device__ __forceinline__ void loadB1(const float* __restrict__ W, int col, int q,
                                       bf16x8 (&Bh)[2], bf16x8 (&Bl)[2]) {
#pragma unroll
    for (int c = 0; c < 2; ++c) {
        const float* src = W + col * 64 + c * 32 + q * 8;
        const float4 a = reinterpret_cast<const float4*>(src)[0];
        const float4 b = reinterpret_cast<const float4*>(src)[1];
        float f[8] = {a.x, a.y, a.z, a.w, b.x, b.y, b.z, b.w};
        split8(f, Bh[c], Bl[c]);
    }
}

// fc B-fragment: only cols p<2 are real (fcW is 2x64); others zero.
__device__ __forceinline__ void loadBfc(const float* __restrict__ fcW, int p, int q,
                                        bf16x8 (&Bh)[2], bf16x8 (&Bl)[2]) {
#pragma unroll
    for (int c = 0; c < 2; ++c) {
        float f[8];
#pragma unroll
        for (int j = 0; j < 8; ++j)
            f[j] = (p < 2) ? fcW[p * 64 + c * 32 + q * 8 + j] : 0.f;
        split8(f, Bh[c], Bl[c]);
    }
}

// G = w0 (x) fcW[0] + w1 (x) fcW[1]  (rank-2 folded feedback matrix)
// G[k][col] = w0(col)*fcW[0][k] + w1(col)*fcW[1][k]
__device__ __forceinline__ void loadBG(const float* __restrict__ fcW, float w0, float w1,
                                       int q, bf16x8 (&Bh)[2], bf16x8 (&Bl)[2]) {
#pragma unroll
    for (int c = 0; c < 2; ++c) {
        float f[8];
#pragma unroll
        for (int j = 0; j < 8; ++j) {
            const int k = c * 32 + q * 8 + j;
            f[j] = w0 * fcW[k] + w1 * fcW[64 + k];
        }
        split8(f, Bh[c], Bl[c]);
    }
}

// split h into hi/lo bf16 and store to the two planes
__device__ __forceinline__ void write_h(unsigned short* hi, unsigned short* lo,
                                        int idx, float h) {
    const unsigned u = __float_as_uint(h);
    hi[idx] = (unsigned short)(u >> 16);
    const float hf = __uint_as_float(u & 0xFFFF0000u);
    const float l  = h - hf;                        // exact
    lo[idx] = (unsigned short)(__float_as_uint(l) >> 16);
}

__device__ __forceinline__ bf16x8 read_frag(const unsigned short* plane, int off) {
    return *reinterpret_cast<const bf16x8*>(plane + off);
}

// 3-term Markidis accumulate: D += Ah*Bh + Ah*Bl + Al*Bh
__device__ __forceinline__ f32x4 mfma3(bf16x8 ah, bf16x8 al, bf16x8 bh, bf16x8 bl, f32x4 acc) {
    acc = __builtin_amdgcn_mfma_f32_16x16x32_bf16(ah, bh, acc, 0, 0, 0);
    acc = __builtin_amdgcn_mfma_f32_16x16x32_bf16(ah, bl, acc, 0, 0, 0);
    acc = __builtin_amdgcn_mfma_f32_16x16x32_bf16(al, bh, acc, 0, 0, 0);
    return acc;
}

__device__ __forceinline__ float fast_tanh(float x) {
    const float e = __expf(2.0f * x);
    return 1.0f - 2.0f / (e + 1.0f);
}

__global__ __launch_bounds__(256) void traj_rnn_kernel(
    const float* __restrict__ x,
    const float* __restrict__ eWih0, const float* __restrict__ eWhh0,
    const float* __restrict__ ebih0, const float* __restrict__ ebhh0,
    const float* __restrict__ eWih1, const float* __restrict__ eWhh1,
    const float* __restrict__ ebih1, const float* __restrict__ ebhh1,
    const float* __restrict__ dWih0, const float* __restrict__ dWhh0,
    const float* __restrict__ dbih0, const float* __restrict__ dbhh0,
    const float* __restrict__ dWih1, const float* __restrict__ dWhh1,
    const float* __restrict__ dbih1, const float* __restrict__ dbhh1,
    const float* __restrict__ fcW, const float* __restrict__ fcb,
    float* __restrict__ out)
{
    const int tid  = threadIdx.x;
    const int wv   = tid >> 6;          // n-tile owned by this wave (0..3)
    const int lane = tid & 63;
    const int p    = lane & 15;         // A-m / C-col-within-tile
    const int q    = lane >> 4;         // k-quad / C row-quad
    const int col  = wv * 16 + p;       // this lane's hidden-unit column
    const int r0   = blockIdx.x * kM;

    __shared__ __align__(16) unsigned short Hhi1[kM * kStrH], Hlo1[kM * kStrH];
    __shared__ __align__(16) unsigned short Hhi2[kM * kStrH], Hlo2[kM * kStrH];
    __shared__ __align__(16) float xbuf[kM * kTH * 2];

    for (int i = tid; i < kM * kTH * 2; i += 256)
        xbuf[i] = x[r0 * (kTH * 2) + i];

    bf16x8 H1h[2], H1l[2], H2h[2], H2l[2];
#pragma unroll
    for (int c = 0; c < 2; ++c) {
        H1h[c] = zero_frag(); H1l[c] = zero_frag();
        H2h[c] = zero_frag(); H2l[c] = zero_frag();
    }
    __syncthreads();

    const int aoff = p * kStrH;  // A-fragment base for this lane's m-row

    // ================= encoder: 11 steps =================
    {
        const float b0 = ebih0[col] + ebhh0[col];
        const float b1 = ebih1[col] + ebhh1[col];
        const float w0 = eWih0[col * 2 + 0];
        const float w1 = eWih0[col * 2 + 1];
        bf16x8 B0h[2], B0l[2], B1h[2], B1l[2], B2h[2], B2l[2];
        loadB1(eWhh0, col, q, B0h, B0l);   // Whh0
        loadB1(eWih1, col, q, B1h, B1l);   // Wih1
        loadB1(eWhh1, col, q, B2h, B2l);   // Whh1

        f32x4 P1 = {b0, b0, b0, b0};       // b0 + Whh0 . h1 (h1 = 0 initially)

#pragma unroll 1
        for (int t = 0; t < kTH; ++t) {
#pragma unroll
            for (int r = 0; r < 4; ++r) {
                const float2 xv = *reinterpret_cast<const float2*>(
                    &xbuf[(4 * q + r) * (kTH * 2) + 2 * t]);
                const float h1 = fast_tanh(fmaf(w0, xv.x, fmaf(w1, xv.y, P1[r])));
                write_h(Hhi1, Hlo1, (4 * q + r) * kStrH + col, h1);
            }
            // layer-2 partial on OLD H2 (independent of h1') before the barrier
            f32x4 a2 = {b1, b1, b1, b1};
#pragma unroll
            for (int c = 0; c < 2; ++c)
                a2 = mfma3(H2h[c], H2l[c], B2h[c], B2l[c], a2);
            __syncthreads();   // h1' visible

#pragma unroll
            for (int c = 0; c < 2; ++c) {
                H1h[c] = read_frag(Hhi1, aoff + c * 32 + q * 8);
                H1l[c] = read_frag(Hlo1, aoff + c * 32 + q * 8);
            }
#pragma unroll
            for (int c = 0; c < 2; ++c)
                a2 = mfma3(H1h[c], H1l[c], B1h[c], B1l[c], a2);
            f32x4 np = {b0, b0, b0, b0};
#pragma unroll
            for (int c = 0; c < 2; ++c)
                np = mfma3(H1h[c], H1l[c], B0h[c], B0l[c], np);
            P1 = np;

#pragma unroll
            for (int r = 0; r < 4; ++r) {
                const float h2 = fast_tanh(a2[r]);
                write_h(Hhi2, Hlo2, (4 * q + r) * kStrH + col, h2);
            }
            __syncthreads();   // h2' visible
#pragma unroll
            for (int c = 0; c < 2; ++c) {
                H2h[c] = read_frag(Hhi2, aoff + c * 32 + q * 8);
                H2l[c] = read_frag(Hlo2, aoff + c * 32 + q * 8);
            }
        }
    }

    // ================= decoder: 80 autoregressive steps =================
    {
        const float b0 = dbih0[col] + dbhh0[col];
        const float b1 = dbih1[col] + dbhh1[col];
        const float w0 = dWih0[col * 2 + 0];
        const float w1 = dWih0[col * 2 + 1];
        const float fb0 = fcb[0];
        const float fb1 = fcb[1];
        // folded bias: feedback constant term absorbed into layer-1 bias
        const float b0p = b0 + w0 * fb0 + w1 * fb1;
        const float fbp = (p == 0) ? fb0 : fb1;   // for direct store from p<2 lanes
        bf16x8 B0h[2], B0l[2], B1h[2], B1l[2], B2h[2], B2l[2];
        bf16x8 BFh[2], BFl[2], BGh[2], BGl[2];
        loadB1(dWhh0, col, q, B0h, B0l);
        loadB1(dWih1, col, q, B1h, B1l);
        loadB1(dWhh1, col, q, B2h, B2l);
        loadBfc(fcW, p, q, BFh, BFl);
        loadBG(fcW, w0, w1, q, BGh, BGl);   // rank-2 folded feedback matrix

        // P1 for the FIRST decoder step: b0 + Whh0.h1_enc + w0*x_last0 + w1*x_last1
        f32x4 P1 = {b0, b0, b0, b0};
#pragma unroll
        for (int c = 0; c < 2; ++c)
            P1 = mfma3(H1h[c], H1l[c], B0h[c], B0l[c], P1);
#pragma unroll
        for (int r = 0; r < 4; ++r) {
            const float2 xv = *reinterpret_cast<const float2*>(
                &xbuf[(4 * q + r) * (kTH * 2) + 2 * (kTH - 1)]);
            P1[r] = fmaf(w0, xv.x, fmaf(w1, xv.y, P1[r]));
        }

#pragma unroll 1
        for (int t = 0; t < kTP; ++t) {
            // layer 1: P1 is already complete (bias + recurrent + folded feedback)
#pragma unroll
            for (int r = 0; r < 4; ++r) {
                const float h1 = fast_tanh(P1[r]);
                write_h(Hhi1, Hlo1, (4 * q + r) * kStrH + col, h1);
            }
            // layer-2 partial on OLD H2 before the barrier
            f32x4 a2 = {b1, b1, b1, b1};
#pragma unroll
            for (int c = 0; c < 2; ++c)
                a2 = mfma3(H2h[c], H2l[c], B2h[c], B2l[c], a2);
            __syncthreads();   // h1' visible

#pragma unroll
            for (int c = 0; c < 2; ++c) {
                H1h[c] = read_frag(Hhi1, aoff + c * 32 + q * 8);
                H1l[c] = read_frag(Hlo1, aoff + c * 32 + q * 8);
            }
#pragma unroll
            for (int c = 0; c < 2; ++c)
                a2 = mfma3(H1h[c], H1l[c], B1h[c], B1l[c], a2);
            // start next step's P1: folded bias + Whh0 . h1'
            f32x4 np = {b0p, b0p, b0p, b0p};
#pragma unroll
            for (int c = 0; c < 2; ++c)
                np = mfma3(H1h[c], H1l[c], B0h[c], B0l[c], np);

#pragma unroll
            for (int r = 0; r < 4; ++r) {
                const float h2 = fast_tanh(a2[r]);
                write_h(Hhi2, Hlo2, (4 * q + r) * kStrH + col, h2);
            }
            __syncthreads();   // h2' visible

#pragma unroll
            for (int c = 0; c < 2; ++c) {
                H2h[c] = read_frag(Hhi2, aoff + c * 32 + q * 8);
                H2l[c] = read_frag(Hlo2, aoff + c * 32 + q * 8);
            }
            // finish next P1 with the folded feedback term G . h2'
#pragma unroll
            for (int c = 0; c < 2; ++c)
                np = mfma3(H2h[c], H2l[c], BGh[c], BGl[c], np);
            P1 = np;

            // pred output only needed on wave 0 (wave-uniform branch)
            if (wv == 0) {
                f32x4 fcC = {0.f, 0.f, 0.f, 0.f};
#pragma unroll
                for (int c = 0; c < 2; ++c)
                    fcC = mfma3(H2h[c], H2l[c], BFh[c], BFl[c], fcC);
                if (p < 2) {
#pragma unroll
                    for (int r = 0; r < 4; ++r)
                        out[((r0 + 4 * q + r) * kTP + t) * 2 + p] = fcC[r] + fbp;
                }
            }
        }
    }
}

extern "C" void kernel_launch(void* const* d_in, const int* in_sizes, int n_in,
                              void* d_out, int out_size, void* d_ws, size_t ws_size,
                              hipStream_t stream) {
    const float* x     = (const float*)d_in[0];
    const float* eWih0 = (const float*)d_in[1];
    const float* eWhh0 = (const float*)d_in[2];
    const float* ebih0 = (const float*)d_in[3];
    const float* ebhh0 = (const float*)d_in[4];
    const float* eWih1 = (const float*)d_in[5];
    const float* eWhh1 = (const float*)d_in[6];
    const float* ebih1 = (const float*)d_in[7];
    const float* ebhh1 = (const float*)d_in[8];
    const float* dWih0 = (const float*)d_in[9];
    const float* dWhh0 = (const float*)d_in[10];
    const float* dbih0 = (const float*)d_in[11];
    const float* dbhh0 = (const float*)d_in[12];
    const float* dWih1 = (const float*)d_in[13];
    const float* dWhh1 = (const float*)d_in[14];
    const float* dbih1 = (const float*)d_in[15];
    const float* dbhh1 = (const float*)d_in[16];
    const float* fcW   = (const float*)d_in[17];
    const float* fcb   = (const float*)d_in[18];
    float* out = (float*)d_out;

    dim3 grid(kB / kM);   // 512 blocks x 4 waves; wave n owns output cols 16n..16n+15
    dim3 block(256);
    traj_rnn_kernel<<<grid, block, 0, stream>>>(
        x, eWih0, eWhh0, ebih0, ebhh0, eWih1, eWhh1, ebih1, ebhh1,
        dWih0, dWhh0, dbih0, dbhh0, dWih1, dWhh1, dbih1, dbhh1,
        fcW, fcb, out);
}

// Round 7
// 192.284 us; speedup vs baseline: 4.0398x; 1.0129x over previous
//
#include <hip/hip_runtime.h>

typedef __attribute__((ext_vector_type(8))) __bf16 bf16x8;
typedef __attribute__((ext_vector_type(4))) float  f32x4;

namespace {
constexpr int kB    = 8192;
constexpr int kTH   = 11;
constexpr int kTP   = 80;
constexpr int kM    = 16;    // batch rows per block (MFMA M)
constexpr int kStrH = 72;    // H-plane row stride in bf16 units (144 B: 16B-aligned, 2-way banks)
}

union FragU { bf16x8 v; unsigned u[4]; };

__device__ __forceinline__ bf16x8 zero_frag() {
    FragU z; z.u[0] = z.u[1] = z.u[2] = z.u[3] = 0u; return z.v;
}

__device__ __forceinline__ unsigned pack_hi16(unsigned a, unsigned b) {
    return (a >> 16) | (b & 0xFFFF0000u);
}

// fp32[8] -> hi bf16x8 (truncated) + lo bf16x8 (exact remainder, truncated)
__device__ __forceinline__ void split8(const float* f, bf16x8& hi, bf16x8& lo) {
    FragU H, L;
#pragma unroll
    for (int w = 0; w < 4; ++w) {
        const unsigned u0 = __float_as_uint(f[2 * w + 0]);
        const unsigned u1 = __float_as_uint(f[2 * w + 1]);
        const float h0 = __uint_as_float(u0 & 0xFFFF0000u);
        const float h1 = __uint_as_float(u1 & 0xFFFF0000u);
        const unsigned l0 = __float_as_uint(f[2 * w + 0] - h0);
        const unsigned l1 = __float_as_uint(f[2 * w + 1] - h1);
        H.u[w] = pack_hi16(u0, u1);
        L.u[w] = pack_hi16(l0, l1);
    }
    hi = H.v; lo = L.v;
}

// B-fragments (hi/lo) for column `col`: B[k][col] = W[col][k].
__device__ __forceinline__ void loadB1(const float* __restrict__ W, int col, int q,
                                       bf16x8 (&Bh)[2], bf16x8 (&Bl)[2]) {
#pragma unroll
    for (int c = 0; c < 2; ++c) {
        const float* src = W + col * 64 + c * 32 + q * 8;
        const float4 a = reinterpret_cast<const float4*>(src)[0];
        const float4 b = reinterpret_cast<const float4*>(src)[1];
        float f[8] = {a.x, a.y, a.z, a.w, b.x, b.y, b.z, b.w};
        split8(f, Bh[c], Bl[c]);
    }
}

// fc B-fragment: only cols p<2 are real (fcW is 2x64); others zero.
__device__ __forceinline__ void loadBfc(const float* __restrict__ fcW, int p, int q,
                                        bf16x8 (&Bh)[2], bf16x8 (&Bl)[2]) {
#pragma unroll
    for (int c = 0; c < 2; ++c) {
        float f[8];
#pragma unroll
        for (int j = 0; j < 8; ++j)
            f[j] = (p < 2) ? fcW[p * 64 + c * 32 + q * 8 + j] : 0.f;
        split8(f, Bh[c], Bl[c]);
    }
}

// G = w0 (x) fcW[0] + w1 (x) fcW[1]  (rank-2 folded feedback matrix)
// G[k][col] = w0(col)*fcW[0][k] + w1(col)*fcW[1][k]
__device__ __forceinline__ void loadBG(const float* __restrict__ fcW, float w0, float w1,
                                       int q, bf16x8 (&Bh)[2], bf16x8 (&Bl)[2]) {
#pragma unroll
    for (int c = 0; c < 2; ++c) {
        float f[8];
#pragma unroll
        for (int j = 0; j < 8; ++j) {
            const int k = c * 32 + q * 8 + j;
            f[j] = w0 * fcW[k] + w1 * fcW[64 + k];
        }
        split8(f, Bh[c], Bl[c]);
    }
}

// split h into hi/lo bf16 and store to the two planes
__device__ __forceinline__ void write_h(unsigned short* hi, unsigned short* lo,
                                        int idx, float h) {
    const unsigned u = __float_as_uint(h);
    hi[idx] = (unsigned short)(u >> 16);
    const float hf = __uint_as_float(u & 0xFFFF0000u);
    const float l  = h - hf;                        // exact
    lo[idx] = (unsigned short)(__float_as_uint(l) >> 16);
}

__device__ __forceinline__ bf16x8 read_frag(const unsigned short* plane, int off) {
    return *reinterpret_cast<const bf16x8*>(plane + off);
}

// 3-term Markidis accumulate: D += Ah*Bh + Ah*Bl + Al*Bh
__device__ __forceinline__ f32x4 mfma3(bf16x8 ah, bf16x8 al, bf16x8 bh, bf16x8 bl, f32x4 acc) {
    acc = __builtin_amdgcn_mfma_f32_16x16x32_bf16(ah, bh, acc, 0, 0, 0);
    acc = __builtin_amdgcn_mfma_f32_16x16x32_bf16(ah, bl, acc, 0, 0, 0);
    acc = __builtin_amdgcn_mfma_f32_16x16x32_bf16(al, bh, acc, 0, 0, 0);
    return acc;
}

__device__ __forceinline__ float fast_tanh(float x) {
    const float e = __expf(2.0f * x);
    return 1.0f - 2.0f / (e + 1.0f);
}

// waves_per_eu(2,2): grid caps occupancy at 2 waves/SIMD anyway (2048 waves /
// 1024 SIMDs); requesting it explicitly gives the allocator the full ~256-VGPR
// budget so MFMA accumulators/fragments stay in arch VGPRs (no v_accvgpr shuttles).
__global__ __attribute__((amdgpu_waves_per_eu(2, 2))) __launch_bounds__(256)
void traj_rnn_kernel(
    const float* __restrict__ x,
    const float* __restrict__ eWih0, const float* __restrict__ eWhh0,
    const float* __restrict__ ebih0, const float* __restrict__ ebhh0,
    const float* __restrict__ eWih1, const float* __restrict__ eWhh1,
    const float* __restrict__ ebih1, const float* __restrict__ ebhh1,
    const float* __restrict__ dWih0, const float* __restrict__ dWhh0,
    const float* __restrict__ dbih0, const float* __restrict__ dbhh0,
    const float* __restrict__ dWih1, const float* __restrict__ dWhh1,
    const float* __restrict__ dbih1, const float* __restrict__ dbhh1,
    const float* __restrict__ fcW, const float* __restrict__ fcb,
    float* __restrict__ out)
{
    const int tid  = threadIdx.x;
    const int wv   = tid >> 6;          // n-tile owned by this wave (0..3)
    const int lane = tid & 63;
    const int p    = lane & 15;         // A-m / C-col-within-tile
    const int q    = lane >> 4;         // k-quad / C row-quad
    const int col  = wv * 16 + p;       // this lane's hidden-unit column
    const int r0   = blockIdx.x * kM;

    __shared__ __align__(16) unsigned short Hhi1[kM * kStrH], Hlo1[kM * kStrH];
    __shared__ __align__(16) unsigned short Hhi2[kM * kStrH], Hlo2[kM * kStrH];
    __shared__ __align__(16) float xbuf[kM * kTH * 2];

    for (int i = tid; i < kM * kTH * 2; i += 256)
        xbuf[i] = x[r0 * (kTH * 2) + i];

    bf16x8 H1h[2], H1l[2], H2h[2], H2l[2];
#pragma unroll
    for (int c = 0; c < 2; ++c) {
        H1h[c] = zero_frag(); H1l[c] = zero_frag();
        H2h[c] = zero_frag(); H2l[c] = zero_frag();
    }
    __syncthreads();

    const int aoff = p * kStrH;  // A-fragment base for this lane's m-row

    // ================= encoder: 11 steps =================
    {
        const float b0 = ebih0[col] + ebhh0[col];
        const float b1 = ebih1[col] + ebhh1[col];
        const float w0 = eWih0[col * 2 + 0];
        const float w1 = eWih0[col * 2 + 1];
        bf16x8 B0h[2], B0l[2], B1h[2], B1l[2], B2h[2], B2l[2];
        loadB1(eWhh0, col, q, B0h, B0l);   // Whh0
        loadB1(eWih1, col, q, B1h, B1l);   // Wih1
        loadB1(eWhh1, col, q, B2h, B2l);   // Whh1

        f32x4 P1 = {b0, b0, b0, b0};       // b0 + Whh0 . h1 (h1 = 0 initially)

#pragma unroll 1
        for (int t = 0; t < kTH; ++t) {
#pragma unroll
            for (int r = 0; r < 4; ++r) {
                const float2 xv = *reinterpret_cast<const float2*>(
                    &xbuf[(4 * q + r) * (kTH * 2) + 2 * t]);
                const float h1 = fast_tanh(fmaf(w0, xv.x, fmaf(w1, xv.y, P1[r])));
                write_h(Hhi1, Hlo1, (4 * q + r) * kStrH + col, h1);
            }
            // layer-2 partial on OLD H2 (independent of h1') before the barrier
            f32x4 a2 = {b1, b1, b1, b1};
#pragma unroll
            for (int c = 0; c < 2; ++c)
                a2 = mfma3(H2h[c], H2l[c], B2h[c], B2l[c], a2);
            __syncthreads();   // h1' visible

#pragma unroll
            for (int c = 0; c < 2; ++c) {
                H1h[c] = read_frag(Hhi1, aoff + c * 32 + q * 8);
                H1l[c] = read_frag(Hlo1, aoff + c * 32 + q * 8);
            }
#pragma unroll
            for (int c = 0; c < 2; ++c)
                a2 = mfma3(H1h[c], H1l[c], B1h[c], B1l[c], a2);
            f32x4 np = {b0, b0, b0, b0};
#pragma unroll
            for (int c = 0; c < 2; ++c)
                np = mfma3(H1h[c], H1l[c], B0h[c], B0l[c], np);
            P1 = np;

#pragma unroll
            for (int r = 0; r < 4; ++r) {
                const float h2 = fast_tanh(a2[r]);
                write_h(Hhi2, Hlo2, (4 * q + r) * kStrH + col, h2);
            }
            __syncthreads();   // h2' visible
#pragma unroll
            for (int c = 0; c < 2; ++c) {
                H2h[c] = read_frag(Hhi2, aoff + c * 32 + q * 8);
                H2l[c] = read_frag(Hlo2, aoff + c * 32 + q * 8);
            }
        }
    }

    // ================= decoder: 80 autoregressive steps =================
    {
        const float b0 = dbih0[col] + dbhh0[col];
        const float b1 = dbih1[col] + dbhh1[col];
        const float w0 = dWih0[col * 2 + 0];
        const float w1 = dWih0[col * 2 + 1];
        const float fb0 = fcb[0];
        const float fb1 = fcb[1];
        // folded bias: feedback constant term absorbed into layer-1 bias
        const float b0p = b0 + w0 * fb0 + w1 * fb1;
        const float fbp = (p == 0) ? fb0 : fb1;   // for direct store from p<2 lanes
        bf16x8 B0h[2], B0l[2], B1h[2], B1l[2], B2h[2], B2l[2];
        bf16x8 BFh[2], BFl[2], BGh[2], BGl[2];
        loadB1(dWhh0, col, q, B0h, B0l);
        loadB1(dWih1, col, q, B1h, B1l);
        loadB1(dWhh1, col, q, B2h, B2l);
        loadBfc(fcW, p, q, BFh, BFl);
        loadBG(fcW, w0, w1, q, BGh, BGl);   // rank-2 folded feedback matrix

        // P1 for the FIRST decoder step: b0 + Whh0.h1_enc + w0*x_last0 + w1*x_last1
        f32x4 P1 = {b0, b0, b0, b0};
#pragma unroll
        for (int c = 0; c < 2; ++c)
            P1 = mfma3(H1h[c], H1l[c], B0h[c], B0l[c], P1);
#pragma unroll
        for (int r = 0; r < 4; ++r) {
            const float2 xv = *reinterpret_cast<const float2*>(
                &xbuf[(4 * q + r) * (kTH * 2) + 2 * (kTH - 1)]);
            P1[r] = fmaf(w0, xv.x, fmaf(w1, xv.y, P1[r]));
        }

#pragma unroll 1
        for (int t = 0; t < kTP; ++t) {
            // layer 1: P1 is already complete (bias + recurrent + folded feedback)
#pragma unroll
            for (int r = 0; r < 4; ++r) {
                const float h1 = fast_tanh(P1[r]);
                write_h(Hhi1, Hlo1, (4 * q + r) * kStrH + col, h1);
            }
            // layer-2 partial on OLD H2 before the barrier
            f32x4 a2 = {b1, b1, b1, b1};
#pragma unroll
            for (int c = 0; c < 2; ++c)
                a2 = mfma3(H2h[c], H2l[c], B2h[c], B2l[c], a2);
            __syncthreads();   // h1' visible

#pragma unroll
            for (int c = 0; c < 2; ++c) {
                H1h[c] = read_frag(Hhi1, aoff + c * 32 + q * 8);
                H1l[c] = read_frag(Hlo1, aoff + c * 32 + q * 8);
            }
#pragma unroll
            for (int c = 0; c < 2; ++c)
                a2 = mfma3(H1h[c], H1l[c], B1h[c], B1l[c], a2);
            // start next step's P1: folded bias + Whh0 . h1'
            f32x4 np = {b0p, b0p, b0p, b0p};
#pragma unroll
            for (int c = 0; c < 2; ++c)
                np = mfma3(H1h[c], H1l[c], B0h[c], B0l[c], np);

#pragma unroll
            for (int r = 0; r < 4; ++r) {
                const float h2 = fast_tanh(a2[r]);
                write_h(Hhi2, Hlo2, (4 * q + r) * kStrH + col, h2);
            }
            __syncthreads();   // h2' visible

#pragma unroll
            for (int c = 0; c < 2; ++c) {
                H2h[c] = read_frag(Hhi2, aoff + c * 32 + q * 8);
                H2l[c] = read_frag(Hlo2, aoff + c * 32 + q * 8);
            }
            // finish next P1 with the folded feedback term G . h2'
#pragma unroll
            for (int c = 0; c < 2; ++c)
                np = mfma3(H2h[c], H2l[c], BGh[c], BGl[c], np);
            P1 = np;

            // pred output only needed on wave 0 (wave-uniform branch)
            if (wv == 0) {
                f32x4 fcC = {0.f, 0.f, 0.f, 0.f};
#pragma unroll
                for (int c = 0; c < 2; ++c)
                    fcC = mfma3(H2h[c], H2l[c], BFh[c], BFl[c], fcC);
                if (p < 2) {
#pragma unroll
                    for (int r = 0; r < 4; ++r)
                        out[((r0 + 4 * q + r) * kTP + t) * 2 + p] = fcC[r] + fbp;
                }
            }
        }
    }
}

extern "C" void kernel_launch(void* const* d_in, const int* in_sizes, int n_in,
                              void* d_out, int out_size, void* d_ws, size_t ws_size,
                              hipStream_t stream) {
    const float* x     = (const float*)d_in[0];
    const float* eWih0 = (const float*)d_in[1];
    const float* eWhh0 = (const float*)d_in[2];
    const float* ebih0 = (const float*)d_in[3];
    const float* ebhh0 = (const float*)d_in[4];
    const float* eWih1 = (const float*)d_in[5];
    const float* eWhh1 = (const float*)d_in[6];
    const float* ebih1 = (const float*)d_in[7];
    const float* ebhh1 = (const float*)d_in[8];
    const float* dWih0 = (const float*)d_in[9];
    const float* dWhh0 = (const float*)d_in[10];
    const float* dbih0 = (const float*)d_in[11];
    const float* dbhh0 = (const float*)d_in[12];
    const float* dWih1 = (const float*)d_in[13];
    const float* dWhh1 = (const float*)d_in[14];
    const float* dbih1 = (const float*)d_in[15];
    const float* dbhh1 = (const float*)d_in[16];
    const float* fcW   = (const float*)d_in[17];
    const float* fcb   = (const float*)d_in[18];
    float* out = (float*)d_out;

    dim3 grid(kB / kM);   // 512 blocks x 4 waves; wave n owns output cols 16n..16n+15
    dim3 block(256);
    traj_rnn_kernel<<<grid, block, 0, stream>>>(
        x, eWih0, eWhh0, ebih0, ebhh0, eWih1, eWhh1, ebih1, ebhh1,
        dWih0, dWhh0, dbih0, dbhh0, dWih1, dWhh1, dbih1, dbhh1,
        fcW, fcb, out);
}